// Round 8
// baseline (362.848 us; speedup 1.0000x reference)
//
#include <hip/hip_runtime.h>

// MHA forward: B=2, S=2048, HID=1024, NH=16, HD=64.
// R8: R7's register-pipelined GEMM retried with __launch_bounds__(256,3):
//     R7 spilled (WRITE_SIZE 24->64MB = scratch) because default VGPR target
//     (116) < demand (~140). Cap 170 keeps 3 waves/SIMD spill-free.
//     Attention: same register-prefetch of K/V tiles (+16 VGPR, LB (512,4)),
//     removing the fully-exposed per-kv staging drain. Out-proj: 128x64 tiles
//     -> 512 blocks (2/CU, was 1/CU).

typedef unsigned short u16;
typedef unsigned int u32;
typedef __bf16 bf16x8 __attribute__((ext_vector_type(8)));
typedef float f32x4 __attribute__((ext_vector_type(4)));
typedef u16 u16x4 __attribute__((ext_vector_type(4)));

__device__ __forceinline__ u16 f2bf(float f) {
  __bf16 h = (__bf16)f;            // RNE hw cvt
  return *(u16*)&h;
}

// ---------------- prep: 4 weight transposes ----------------
__global__ void transpose4_kernel(
    const float* __restrict__ W0, const float* __restrict__ W1,
    const float* __restrict__ W2, const float* __restrict__ W3,
    u16* __restrict__ T0, u16* __restrict__ T1,
    u16* __restrict__ T2, u16* __restrict__ T3) {
  const float* W = (blockIdx.z == 0) ? W0 : (blockIdx.z == 1) ? W1
                  : (blockIdx.z == 2) ? W2 : W3;
  u16* WT = (blockIdx.z == 0) ? T0 : (blockIdx.z == 1) ? T1
           : (blockIdx.z == 2) ? T2 : T3;
  __shared__ float t[32][33];
  int bx = blockIdx.x * 32, by = blockIdx.y * 32;
  int tx = threadIdx.x, ty = threadIdx.y;
#pragma unroll
  for (int i = ty; i < 32; i += 8) t[i][tx] = W[(by + i) * 1024 + bx + tx];
  __syncthreads();
#pragma unroll
  for (int i = ty; i < 32; i += 8) WT[(bx + i) * 1024 + by + tx] = f2bf(t[tx][i]);
}

// ---------------- GEMM (register-pipelined) ----------------
// C[M=4096, N=1024] = A * B + bias; BT = B^T bf16. Tile 128 x BN, BK=64.
// Per iter: barrier -> ds_write staged regs (vmcnt wait lands here) ->
// barrier -> issue next tile's global loads -> MFMA from LDS.
struct GemmJob {
  const void* A; const u16* BT; const float* bias;
  float* Cf; u16* Cb; int mode; float oscale;
};

template <bool F32A, int BN>
__global__ __launch_bounds__(256, 3) void gemm_multi(GemmJob j0, GemmJob j1, GemmJob j2) {
  constexpr int NT = BN / 32;          // nt groups per wave (4 or 2)
  constexpr int NBC = BN / 32;         // B staging chunks per thread (4 or 2)
  int blk = blockIdx.x;
  const int K = 1024, N = 1024;
  // job select: QKV path has 256 blocks/job (BN=128); out path single job
  int z, r0;
  if (BN == 128) { z = blk >> 8; r0 = blk & 255; }
  else { z = 0; r0 = blk; }
  GemmJob j = (z == 0) ? j0 : (z == 1) ? j1 : j2;
  __shared__ __align__(16) u16 As[128 * 64];
  __shared__ __align__(16) u16 Bs[BN * 64];
  int tid = threadIdx.x;
  int bm, bn;
  if (BN == 128) {
    int xcd = r0 & 7, i5 = r0 >> 3;
    bm = (xcd * 4 + (i5 & 3)) * 128;
    bn = (i5 >> 2) * 128;
  } else {  // 512 blocks: xcd owns 4 bm x 16 bn
    int xcd = r0 & 7, i6 = r0 >> 3;
    bm = (xcd * 4 + (i6 & 3)) * 128;
    bn = (i6 >> 2) * 64;
  }
  int w = tid >> 6, lane = tid & 63, quad = lane >> 4, l16 = lane & 15;
  int wr = (w >> 1) * 64, wc = (w & 1) * (BN / 2);
  f32x4 acc[4][NT] = {};

  float4 argf[8];
  uint4  argb[4];
  uint4  brg[NBC];

  const float* Af = (const float*)j.A;
  const u16*   Ab = (const u16*)j.A;

  // prologue: tile 0 -> regs
  if (F32A) {
#pragma unroll
    for (int i = 0; i < 8; ++i) {
      int c = tid + i * 256, r = c >> 4, jf = c & 15;
      argf[i] = *(const float4*)&Af[(size_t)(bm + r) * K + jf * 4];
    }
  } else {
#pragma unroll
    for (int i = 0; i < 4; ++i) {
      int c = tid + i * 256, r = c >> 3, jb = c & 7;
      argb[i] = *(const uint4*)&Ab[(size_t)(bm + r) * K + jb * 8];
    }
  }
#pragma unroll
  for (int i = 0; i < NBC; ++i) {
    int c = tid + i * 256, r = c >> 3, jb = c & 7;
    brg[i] = *(const uint4*)&j.BT[(size_t)(bn + r) * K + jb * 8];
  }

  for (int k0 = 0; k0 < K; k0 += 64) {
    __syncthreads();
    if (F32A) {
#pragma unroll
      for (int i = 0; i < 8; ++i) {
        int c = tid + i * 256, r = c >> 4, jf = c & 15;
        u16x4 p;
#pragma unroll
        for (int t = 0; t < 4; ++t) p[t] = f2bf(argf[i][t]);
        *(u16x4*)&As[(r * 8 + ((jf >> 1) ^ (r & 7))) * 8 + (jf & 1) * 4] = p;
      }
    } else {
#pragma unroll
      for (int i = 0; i < 4; ++i) {
        int c = tid + i * 256, r = c >> 3, jb = c & 7;
        *(uint4*)&As[(r * 8 + (jb ^ (r & 7))) * 8] = argb[i];
      }
    }
#pragma unroll
    for (int i = 0; i < NBC; ++i) {
      int c = tid + i * 256, r = c >> 3, jb = c & 7;
      *(uint4*)&Bs[(r * 8 + (jb ^ (r & 7))) * 8] = brg[i];
    }
    __syncthreads();

    int kn = k0 + 64;
    if (kn < K) {
      if (F32A) {
#pragma unroll
        for (int i = 0; i < 8; ++i) {
          int c = tid + i * 256, r = c >> 4, jf = c & 15;
          argf[i] = *(const float4*)&Af[(size_t)(bm + r) * K + kn + jf * 4];
        }
      } else {
#pragma unroll
        for (int i = 0; i < 4; ++i) {
          int c = tid + i * 256, r = c >> 3, jb = c & 7;
          argb[i] = *(const uint4*)&Ab[(size_t)(bm + r) * K + kn + jb * 8];
        }
      }
#pragma unroll
      for (int i = 0; i < NBC; ++i) {
        int c = tid + i * 256, r = c >> 3, jb = c & 7;
        brg[i] = *(const uint4*)&j.BT[(size_t)(bn + r) * K + kn + jb * 8];
      }
    }

#pragma unroll
    for (int ks = 0; ks < 2; ++ks) {
      bf16x8 af[4], bfr[NT];
#pragma unroll
      for (int mt = 0; mt < 4; ++mt) {
        int row = wr + mt * 16 + l16;
        af[mt] = *(const bf16x8*)&As[row * 64 + (((ks * 4 + quad) ^ (row & 7))) * 8];
      }
#pragma unroll
      for (int nt = 0; nt < NT; ++nt) {
        int row = wc + nt * 16 + l16;
        bfr[nt] = *(const bf16x8*)&Bs[row * 64 + (((ks * 4 + quad) ^ (row & 7))) * 8];
      }
#pragma unroll
      for (int mt = 0; mt < 4; ++mt)
#pragma unroll
        for (int nt = 0; nt < NT; ++nt)
          acc[mt][nt] = __builtin_amdgcn_mfma_f32_16x16x32_bf16(af[mt], bfr[nt], acc[mt][nt], 0, 0, 0);
    }
  }

#pragma unroll
  for (int mt = 0; mt < 4; ++mt)
#pragma unroll
    for (int nt = 0; nt < NT; ++nt)
#pragma unroll
      for (int r = 0; r < 4; ++r) {
        int row = bm + wr + mt * 16 + quad * 4 + r;
        int col = bn + wc + nt * 16 + l16;
        float v = (acc[mt][nt][r] + j.bias[col]) * j.oscale;
        if (j.mode == 0) {
          j.Cf[(size_t)row * N + col] = v;
        } else {
          int b = row >> 11, s = row & 2047, h = col >> 6, d = col & 63;
          u16 bv = f2bf(v);
          if (j.mode == 1)
            j.Cb[(((size_t)(b * 16 + h) * 2048 + s) << 6) + d] = bv;
          else
            j.Cb[((size_t)(b * 16 + h) * 64 + d) * 2048 + s] = bv;
        }
      }
}

// ---------------- flash attention (register-prefetched K/V) ----------------
// Flat grid 512, block 512 (8 waves x 16 q-rows). Q pre-scaled (softmax scale
// folded into projection). Per kv-iter: barrier -> ds_write staged K/V regs ->
// barrier -> issue kv+1 loads -> S^T MFMA, exp2, PT round-trip, PV MFMA.
__global__ __launch_bounds__(512, 4) void attn_kernel(
    const u16* __restrict__ Q,   // [B*NH, S, 64] (pre-scaled)
    const u16* __restrict__ Kk,  // [B*NH, S, 64]
    const u16* __restrict__ VT,  // [B*NH, 64, S]
    u16* __restrict__ ctx)       // [B*S, 1024]
{
  __shared__ __align__(16) u16 Ks[128 * 64];
  __shared__ __align__(16) u16 Vs[64 * 128];
  __shared__ __align__(16) u16 PT[8 * 16 * 128];

  int blk = blockIdx.x;
  int qt = (blk >> 3) & 15;
  int bh = (blk & 7) * 4 + (blk >> 7);
  int b = bh >> 4, h = bh & 15;
  const u16* Qb = Q + ((size_t)bh * 2048 + qt * 128) * 64;
  const u16* Kb = Kk + (size_t)bh * 2048 * 64;
  const u16* Vb = VT + (size_t)bh * 64 * 2048;
  int tid = threadIdx.x, w = tid >> 6, lane = tid & 63, quad = lane >> 4, l16 = lane & 15;
  int rowbase = w * 16;
  u16* PTw = &PT[w * 16 * 128];

  bf16x8 qf[2];
#pragma unroll
  for (int ks = 0; ks < 2; ++ks)
    qf[ks] = *(const bf16x8*)&Qb[(rowbase + l16) * 64 + ks * 32 + quad * 8];

  f32x4 Oacc[4] = {};
  float lacc = 0.f;

  // staging regs + addressing (linear global; swizzle applied at LDS write)
  uint4 krg[2], vrg[2];
  int kr[2], kj[2], vd[2], vj[2];
#pragma unroll
  for (int i = 0; i < 2; ++i) {
    int g = tid + i * 512;
    kr[i] = g >> 3; kj[i] = g & 7;
    vd[i] = g >> 4; vj[i] = g & 15;
  }
  // prologue: kv=0
#pragma unroll
  for (int i = 0; i < 2; ++i) {
    krg[i] = *(const uint4*)&Kb[(size_t)kr[i] * 64 + kj[i] * 8];
    vrg[i] = *(const uint4*)&Vb[(size_t)vd[i] * 2048 + vj[i] * 8];
  }

  for (int kv = 0; kv < 16; ++kv) {
    __syncthreads();
#pragma unroll
    for (int i = 0; i < 2; ++i) {
      *(uint4*)&Ks[(kr[i] * 8 + (kj[i] ^ (kr[i] & 7))) * 8] = krg[i];
      *(uint4*)&Vs[(vd[i] * 16 + (vj[i] ^ (vd[i] & 15))) * 8] = vrg[i];
    }
    __syncthreads();

    if (kv < 15) {
      int kb2 = (kv + 1) * 128;
#pragma unroll
      for (int i = 0; i < 2; ++i) {
        krg[i] = *(const uint4*)&Kb[(size_t)(kb2 + kr[i]) * 64 + kj[i] * 8];
        vrg[i] = *(const uint4*)&Vb[(size_t)vd[i] * 2048 + kb2 + vj[i] * 8];
      }
    }

    f32x4 Sacc[8] = {};
#pragma unroll
    for (int nt = 0; nt < 8; ++nt) {
      int r = nt * 16 + l16;
#pragma unroll
      for (int ks = 0; ks < 2; ++ks) {
        bf16x8 kfr = *(const bf16x8*)&Ks[r * 64 + ((ks * 4 + quad) ^ (l16 & 7)) * 8];
        Sacc[nt] = __builtin_amdgcn_mfma_f32_16x16x32_bf16(kfr, qf[ks], Sacc[nt], 0, 0, 0);
      }
    }

#pragma unroll
    for (int nt = 0; nt < 8; ++nt) {
      u16x4 pk;
#pragma unroll
      for (int r = 0; r < 4; ++r) {
        float p = exp2f(Sacc[nt][r]);
        lacc += p;
        pk[r] = f2bf(p);
      }
      int jj = nt * 2 + (quad >> 1);
      *(u16x4*)&PTw[l16 * 128 + ((jj ^ l16) * 8) + (quad & 1) * 4] = pk;
    }

#pragma unroll
    for (int ks2 = 0; ks2 < 4; ++ks2) {
      bf16x8 pfB = *(const bf16x8*)&PTw[l16 * 128 + (((ks2 * 4 + quad) ^ l16)) * 8];
#pragma unroll
      for (int dt = 0; dt < 4; ++dt) {
        int d = dt * 16 + l16;
        bf16x8 vf = *(const bf16x8*)&Vs[d * 128 + (((ks2 * 4 + quad) ^ l16)) * 8];
        Oacc[dt] = __builtin_amdgcn_mfma_f32_16x16x32_bf16(vf, pfB, Oacc[dt], 0, 0, 0);
      }
    }
  }

  float l = lacc;
  l += __shfl_xor(l, 16, 64);
  l += __shfl_xor(l, 32, 64);
  float linv = 1.0f / l;

  int s = qt * 128 + rowbase + l16;
#pragma unroll
  for (int dt = 0; dt < 4; ++dt) {
    u16x4 o;
#pragma unroll
    for (int r = 0; r < 4; ++r) o[r] = f2bf(Oacc[dt][r] * linv);
    *(u16x4*)&ctx[(size_t)(b * 2048 + s) * 1024 + h * 64 + dt * 16 + quad * 4] = o;
  }
}

// ---------------- launch ----------------

extern "C" void kernel_launch(void* const* d_in, const int* in_sizes, int n_in,
                              void* d_out, int out_size, void* d_ws, size_t ws_size,
                              hipStream_t stream) {
  const float* query = (const float*)d_in[0];
  const float* key_  = (const float*)d_in[1];
  const float* value = (const float*)d_in[2];
  const float* Wq = (const float*)d_in[3];
  const float* bq = (const float*)d_in[4];
  const float* Wk = (const float*)d_in[5];
  const float* bk = (const float*)d_in[6];
  const float* Wv = (const float*)d_in[7];
  const float* bv = (const float*)d_in[8];
  const float* Wo = (const float*)d_in[9];
  const float* bo = (const float*)d_in[10];
  float* out = (float*)d_out;

  char* ws = (char*)d_ws;
  const size_t MB = 1024 * 1024;
  u16* WqT = (u16*)(ws + 0 * MB);
  u16* WkT = (u16*)(ws + 2 * MB);
  u16* WvT = (u16*)(ws + 4 * MB);
  u16* WoT = (u16*)(ws + 6 * MB);
  u16* Qp  = (u16*)(ws + 8 * MB);    // [B*NH, S, 64] pre-scaled
  u16* Kp  = (u16*)(ws + 16 * MB);
  u16* VTp = (u16*)(ws + 24 * MB);   // [B*NH, 64, S]
  u16* Ctx = (u16*)(ws + 32 * MB);   // [4096, 1024]

  transpose4_kernel<<<dim3(32, 32, 4), dim3(32, 8), 0, stream>>>(
      Wq, Wk, Wv, Wo, WqT, WkT, WvT, WoT);

  const float sc = 0.125f * 1.44269504f;  // 1/sqrt(64) * log2(e)
  GemmJob jq{query, WqT, bq, nullptr, Qp, 1, sc};
  GemmJob jk{key_, WkT, bk, nullptr, Kp, 1, 1.0f};
  GemmJob jv{value, WvT, bv, nullptr, VTp, 2, 1.0f};
  gemm_multi<true, 128><<<768, 256, 0, stream>>>(jq, jk, jv);

  attn_kernel<<<512, 512, 0, stream>>>(Qp, Kp, VTp, Ctx);

  GemmJob jo{Ctx, WoT, bo, out, nullptr, 0, 1.0f};
  gemm_multi<false, 64><<<512, 256, 0, stream>>>(jo, jo, jo);
}

// Round 9
// 266.835 us; speedup vs baseline: 1.3598x; 1.3598x over previous
//
#include <hip/hip_runtime.h>

// MHA forward: B=2, S=2048, HID=1024, NH=16, HD=64.
// R9: register-staging abandoned (R7/R8 spilled: gfx950 unified VGPR/AGPR file,
//     64-AGPR acc + 48 staging regs don't fit any occupancy>=3 budget).
//     Instead: double-buffered LDS with gll16, issue-before-compute — per iter
//     the next tile's global_load_lds go out BEFORE the MFMA block, so the
//     barrier's mandatory vmcnt(0) drain lands after a full compute window.
//     No long-lived registers -> no spill. A is bf16 (cast pass back in prep);
//     LDS 64KB (QKV, 2 blk/CU) / 48KB (out BN=64, 3 blk/CU, 512 blocks).
//     Attention reverted to R6 exact (78us known).

typedef unsigned short u16;
typedef unsigned int u32;
typedef __bf16 bf16x8 __attribute__((ext_vector_type(8)));
typedef float f32x4 __attribute__((ext_vector_type(4)));
typedef u16 u16x4 __attribute__((ext_vector_type(4)));

__device__ __forceinline__ u16 f2bf(float f) {
  __bf16 h = (__bf16)f;            // RNE hw cvt
  return *(u16*)&h;
}

// async global->LDS, 16 B per lane. LDS dest is wave-uniform base + lane*16.
__device__ __forceinline__ void gll16(const void* g, void* l) {
  __builtin_amdgcn_global_load_lds(
      (const __attribute__((address_space(1))) u32*)g,
      (__attribute__((address_space(3))) u32*)l, 16, 0, 0);
}

// ---------------- prep (single launch, R5 structure) ----------------
// blocks 0..12287: cast query/key_/value fp32->bf16 (4096 blocks each)
// blocks 12288..16383: transpose+cast the 4 weights (1024 blocks each)
__global__ __launch_bounds__(256) void prep_kernel(
    const float* __restrict__ q32, const float* __restrict__ k32,
    const float* __restrict__ v32,
    u16* __restrict__ qb, u16* __restrict__ kb, u16* __restrict__ vb,
    const float* __restrict__ W0, const float* __restrict__ W1,
    const float* __restrict__ W2, const float* __restrict__ W3,
    u16* __restrict__ T0, u16* __restrict__ T1,
    u16* __restrict__ T2, u16* __restrict__ T3) {
  int blk = blockIdx.x, tid = threadIdx.x;
  if (blk < 12288) {
    int which = blk >> 12;
    const float* in = (which == 0) ? q32 : (which == 1) ? k32 : v32;
    u16* out = (which == 0) ? qb : (which == 1) ? kb : vb;
    int i = (blk & 4095) * 256 + tid;
    float4 v = ((const float4*)in)[i];
    u16x4 o;
    o.x = f2bf(v.x); o.y = f2bf(v.y); o.z = f2bf(v.z); o.w = f2bf(v.w);
    ((u16x4*)out)[i] = o;
  } else {
    int tb = blk - 12288;
    int z = tb >> 10, rest = tb & 1023;
    const float* W = (z == 0) ? W0 : (z == 1) ? W1 : (z == 2) ? W2 : W3;
    u16* WT = (z == 0) ? T0 : (z == 1) ? T1 : (z == 2) ? T2 : T3;
    __shared__ float t[32][33];
    int bx = (rest & 31) * 32, by = (rest >> 5) * 32;
    int tx = tid & 31, ty = tid >> 5;
#pragma unroll
    for (int i = ty; i < 32; i += 8) t[i][tx] = W[(by + i) * 1024 + bx + tx];
    __syncthreads();
#pragma unroll
    for (int i = ty; i < 32; i += 8) WT[(bx + i) * 1024 + by + tx] = f2bf(t[tx][i]);
  }
}

// ---------------- GEMM (double-buffered LDS, gll16) ----------------
// C[4096 x 1024] = A(bf16) * B + bias; BT = B^T bf16. Tile 128 x BN, BK=64.
// Per iter: issue gll16(tile i+1 -> buf^1); MFMA from buf; __syncthreads
// (drain overlapped with the MFMA block). XOR swizzle on global fetch index
// (LDS side pinned by gll16); reads verified conflict-free (R6: 0 conflicts).
struct GemmJob {
  const u16* A; const u16* BT; const float* bias;
  float* Cf; u16* Cb; int mode; float oscale;
};

template <int BN>
__global__ __launch_bounds__(256) void gemm_dbuf(GemmJob j0, GemmJob j1, GemmJob j2) {
  constexpr int NT = BN / 32;          // n-tiles per wave
  constexpr int NBC = BN / 32;         // B staging chunks per thread
  const int K = 1024, N = 1024;
  __shared__ __align__(16) u16 As[2][128 * 64];
  __shared__ __align__(16) u16 Bs[2][BN * 64];
  int blk = blockIdx.x, tid = threadIdx.x;
  int z, r0, bm, bn;
  if (BN == 128) {
    z = blk >> 8; r0 = blk & 255;
    int xcd = r0 & 7, i5 = r0 >> 3;
    bm = (xcd * 4 + (i5 & 3)) * 128;
    bn = (i5 >> 2) * 128;
  } else {
    z = 0; r0 = blk;
    int xcd = r0 & 7, i6 = r0 >> 3;
    bm = (xcd * 4 + (i6 & 3)) * 128;
    bn = (i6 >> 2) * 64;
  }
  GemmJob j = (z == 0) ? j0 : (z == 1) ? j1 : j2;
  int w = tid >> 6, lane = tid & 63, quad = lane >> 4, l16 = lane & 15;
  int wr = (w >> 1) * 64, wc = (w & 1) * (BN / 2);
  f32x4 acc[4][NT] = {};

  // stage tile at k-offset kk into buffer sel
  auto stage = [&](int kk, int sel) {
#pragma unroll
    for (int i = 0; i < 4; ++i) {
      int c = tid + i * 256;             // A: 1024 chunks
      int r = c >> 3, jp = c & 7, jg = jp ^ (r & 7);
      gll16(&j.A[(size_t)(bm + r) * K + kk + jg * 8], &As[sel][c * 8]);
    }
#pragma unroll
    for (int i = 0; i < NBC; ++i) {
      int c = tid + i * 256;             // B: BN*8 chunks
      int r = c >> 3, jp = c & 7, jg = jp ^ (r & 7);
      gll16(&j.BT[(size_t)(bn + r) * K + kk + jg * 8], &Bs[sel][c * 8]);
    }
  };

  stage(0, 0);
  __syncthreads();                       // drain tile 0

  for (int it = 0; it < 16; ++it) {
    int cur = it & 1;
    if (it < 15) stage((it + 1) * 64, cur ^ 1);   // issue BEFORE compute
#pragma unroll
    for (int ks = 0; ks < 2; ++ks) {
      bf16x8 af[4], bfr[NT];
#pragma unroll
      for (int mt = 0; mt < 4; ++mt) {
        int row = wr + mt * 16 + l16;
        af[mt] = *(const bf16x8*)&As[cur][row * 64 + (((ks * 4 + quad) ^ (row & 7))) * 8];
      }
#pragma unroll
      for (int nt = 0; nt < NT; ++nt) {
        int row = wc + nt * 16 + l16;
        bfr[nt] = *(const bf16x8*)&Bs[cur][row * 64 + (((ks * 4 + quad) ^ (row & 7))) * 8];
      }
#pragma unroll
      for (int mt = 0; mt < 4; ++mt)
#pragma unroll
        for (int nt = 0; nt < NT; ++nt)
          acc[mt][nt] = __builtin_amdgcn_mfma_f32_16x16x32_bf16(af[mt], bfr[nt], acc[mt][nt], 0, 0, 0);
    }
    __syncthreads();   // drains next tile's loads (issued a full compute window ago)
  }

#pragma unroll
  for (int mt = 0; mt < 4; ++mt)
#pragma unroll
    for (int nt = 0; nt < NT; ++nt)
#pragma unroll
      for (int r = 0; r < 4; ++r) {
        int row = bm + wr + mt * 16 + quad * 4 + r;
        int col = bn + wc + nt * 16 + l16;
        float v = (acc[mt][nt][r] + j.bias[col]) * j.oscale;
        if (j.mode == 0) {
          j.Cf[(size_t)row * N + col] = v;
        } else {
          int b = row >> 11, s = row & 2047, h = col >> 6, d = col & 63;
          u16 bv = f2bf(v);
          if (j.mode == 1)
            j.Cb[(((size_t)(b * 16 + h) * 2048 + s) << 6) + d] = bv;
          else
            j.Cb[((size_t)(b * 16 + h) * 64 + d) * 2048 + s] = bv;
        }
      }
}

// ---------------- flash attention (R6 exact, 78us known) ----------------
__global__ __launch_bounds__(512) void attn_kernel(
    const u16* __restrict__ Q,   // [B*NH, S, 64] (pre-scaled)
    const u16* __restrict__ Kk,  // [B*NH, S, 64]
    const u16* __restrict__ VT,  // [B*NH, 64, S]
    u16* __restrict__ ctx)       // [B*S, 1024]
{
  __shared__ __align__(16) u16 Ks[128 * 64];
  __shared__ __align__(16) u16 Vs[64 * 128];
  __shared__ __align__(16) u16 PT[8 * 16 * 128];

  int blk = blockIdx.x;
  int qt = (blk >> 3) & 15;
  int bh = (blk & 7) * 4 + (blk >> 7);
  int b = bh >> 4, h = bh & 15;
  const u16* Qb = Q + ((size_t)bh * 2048 + qt * 128) * 64;
  const u16* Kb = Kk + (size_t)bh * 2048 * 64;
  const u16* Vb = VT + (size_t)bh * 64 * 2048;
  int tid = threadIdx.x, w = tid >> 6, lane = tid & 63, quad = lane >> 4, l16 = lane & 15;
  int rowbase = w * 16;
  u16* PTw = &PT[w * 16 * 128];

  bf16x8 qf[2];
#pragma unroll
  for (int ks = 0; ks < 2; ++ks)
    qf[ks] = *(const bf16x8*)&Qb[(rowbase + l16) * 64 + ks * 32 + quad * 8];

  f32x4 Oacc[4] = {};
  float lacc = 0.f;

  for (int kv = 0; kv < 16; ++kv) {
    int kbase = kv * 128;
    __syncthreads();
#pragma unroll
    for (int i = 0; i < 2; ++i) {
      int c = tid + i * 512;
      int r = c >> 3, jp = c & 7, jg = jp ^ (r & 7);
      gll16(&Kb[(size_t)(kbase + r) * 64 + jg * 8], &Ks[c * 8]);
    }
#pragma unroll
    for (int i = 0; i < 2; ++i) {
      int c = tid + i * 512;
      int d = c >> 4, jp = c & 15, jg = jp ^ (d & 15);
      gll16(&Vb[(size_t)d * 2048 + kbase + jg * 8], &Vs[c * 8]);
    }
    __syncthreads();

    f32x4 Sacc[8] = {};
#pragma unroll
    for (int nt = 0; nt < 8; ++nt) {
      int r = nt * 16 + l16;
#pragma unroll
      for (int ks = 0; ks < 2; ++ks) {
        bf16x8 kfr = *(const bf16x8*)&Ks[r * 64 + ((ks * 4 + quad) ^ (l16 & 7)) * 8];
        Sacc[nt] = __builtin_amdgcn_mfma_f32_16x16x32_bf16(kfr, qf[ks], Sacc[nt], 0, 0, 0);
      }
    }

#pragma unroll
    for (int nt = 0; nt < 8; ++nt) {
      u16x4 pk;
#pragma unroll
      for (int r = 0; r < 4; ++r) {
        float p = exp2f(Sacc[nt][r]);
        lacc += p;
        pk[r] = f2bf(p);
      }
      int jj = nt * 2 + (quad >> 1);
      *(u16x4*)&PTw[l16 * 128 + ((jj ^ l16) * 8) + (quad & 1) * 4] = pk;
    }

#pragma unroll
    for (int ks2 = 0; ks2 < 4; ++ks2) {
      bf16x8 pfB = *(const bf16x8*)&PTw[l16 * 128 + (((ks2 * 4 + quad) ^ l16)) * 8];
#pragma unroll
      for (int dt = 0; dt < 4; ++dt) {
        int d = dt * 16 + l16;
        bf16x8 vf = *(const bf16x8*)&Vs[d * 128 + (((ks2 * 4 + quad) ^ l16)) * 8];
        Oacc[dt] = __builtin_amdgcn_mfma_f32_16x16x32_bf16(vf, pfB, Oacc[dt], 0, 0, 0);
      }
    }
  }

  float l = lacc;
  l += __shfl_xor(l, 16, 64);
  l += __shfl_xor(l, 32, 64);
  float linv = 1.0f / l;

  int s = qt * 128 + rowbase + l16;
#pragma unroll
  for (int dt = 0; dt < 4; ++dt) {
    u16x4 o;
#pragma unroll
    for (int r = 0; r < 4; ++r) o[r] = f2bf(Oacc[dt][r] * linv);
    *(u16x4*)&ctx[(size_t)(b * 2048 + s) * 1024 + h * 64 + dt * 16 + quad * 4] = o;
  }
}

// ---------------- launch ----------------

extern "C" void kernel_launch(void* const* d_in, const int* in_sizes, int n_in,
                              void* d_out, int out_size, void* d_ws, size_t ws_size,
                              hipStream_t stream) {
  const float* query = (const float*)d_in[0];
  const float* key_  = (const float*)d_in[1];
  const float* value = (const float*)d_in[2];
  const float* Wq = (const float*)d_in[3];
  const float* bq = (const float*)d_in[4];
  const float* Wk = (const float*)d_in[5];
  const float* bk = (const float*)d_in[6];
  const float* Wv = (const float*)d_in[7];
  const float* bv = (const float*)d_in[8];
  const float* Wo = (const float*)d_in[9];
  const float* bo = (const float*)d_in[10];
  float* out = (float*)d_out;

  char* ws = (char*)d_ws;
  const size_t MB = 1024 * 1024;
  u16* Aq  = (u16*)(ws + 0 * MB);
  u16* Ak  = (u16*)(ws + 8 * MB);
  u16* Av  = (u16*)(ws + 16 * MB);
  u16* WqT = (u16*)(ws + 24 * MB);
  u16* WkT = (u16*)(ws + 26 * MB);
  u16* WvT = (u16*)(ws + 28 * MB);
  u16* WoT = (u16*)(ws + 30 * MB);
  u16* Qp  = (u16*)(ws + 32 * MB);   // [B*NH, S, 64] pre-scaled
  u16* Kp  = (u16*)(ws + 40 * MB);
  u16* VTp = (u16*)(ws + 48 * MB);   // [B*NH, 64, S]
  u16* Ctx = (u16*)(ws + 56 * MB);   // [4096, 1024]

  prep_kernel<<<16384, 256, 0, stream>>>(query, key_, value, Aq, Ak, Av,
                                         Wq, Wk, Wv, Wo, WqT, WkT, WvT, WoT);

  const float sc = 0.125f * 1.44269504f;  // 1/sqrt(64) * log2(e)
  GemmJob jq{Aq, WqT, bq, nullptr, Qp, 1, sc};
  GemmJob jk{Ak, WkT, bk, nullptr, Kp, 1, 1.0f};
  GemmJob jv{Av, WvT, bv, nullptr, VTp, 2, 1.0f};
  gemm_dbuf<128><<<768, 256, 0, stream>>>(jq, jk, jv);

  attn_kernel<<<512, 512, 0, stream>>>(Qp, Kp, VTp, Ctx);

  GemmJob jo{Ctx, WoT, bo, out, nullptr, 0, 1.0f};
  gemm_dbuf<64><<<512, 256, 0, stream>>>(jo, jo, jo);
}